// Round 1
// baseline (408.194 us; speedup 1.0000x reference)
//
#include <hip/hip_runtime.h>
#include <hip/hip_bf16.h>

#define O_N 128
#define D_N 128
#define F_LS 64
#define T_MAX 128
#define FE_N 16
#define H_GRU 64
#define NH 128
#define NO 64
#define PH 128

typedef _Float16 f16;
typedef f16 f16x4 __attribute__((ext_vector_type(4)));
typedef f16 f16x8 __attribute__((ext_vector_type(8)));
typedef float f32x4 __attribute__((ext_vector_type(4)));

__device__ __forceinline__ float fast_sigmoid(float x) {
    return __builtin_amdgcn_rcpf(1.f + __expf(-x));
}

// ---------------- encoders + PA/PB precompute (also zeroes d_out) ----------
__global__ __launch_bounds__(128) void k_enc(
    const float* __restrict__ O_feats, const float* __restrict__ D_feats,
    const float* __restrict__ WO1, const float* __restrict__ bO1,
    const float* __restrict__ WO2, const float* __restrict__ bO2,
    const float* __restrict__ WO3, const float* __restrict__ bO3,
    const float* __restrict__ WD1, const float* __restrict__ bD1,
    const float* __restrict__ WD2, const float* __restrict__ bD2,
    const float* __restrict__ WD3, const float* __restrict__ bD3,
    const float* __restrict__ Wp1,
    float* __restrict__ PA, float* __restrict__ PB, float* __restrict__ d_out)
{
    __shared__ float h1[NH];
    __shared__ float h2[NH];
    __shared__ float ev[NO];
    const int b = blockIdx.x;
    const int enc = b >> 7;
    const int row = b & 127;
    const int t = threadIdx.x;
    if (b == 0 && t == 0) d_out[0] = 0.f;

    const float* x  = (enc ? D_feats : O_feats) + row * F_LS;
    const float* W1 = enc ? WD1 : WO1;  const float* b1 = enc ? bD1 : bO1;
    const float* W2 = enc ? WD2 : WO2;  const float* b2 = enc ? bD2 : bO2;
    const float* W3 = enc ? WD3 : WO3;  const float* b3 = enc ? bD3 : bO3;

    float a = b1[t];
    #pragma unroll 8
    for (int k = 0; k < F_LS; ++k) a += x[k] * W1[k * NH + t];
    h1[t] = fmaxf(a, 0.f);
    __syncthreads();

    a = b2[t];
    #pragma unroll 8
    for (int k = 0; k < NH; ++k) a += h1[k] * W2[k * NH + t];
    h2[t] = fmaxf(a, 0.f);
    __syncthreads();

    if (t < NO) {
        a = b3[t];
        #pragma unroll 8
        for (int k = 0; k < NH; ++k) a += h2[k] * W3[k * NO + t];
        ev[t] = a;
    }
    __syncthreads();

    const float* Wp = Wp1 + (enc ? NO * PH : 0);
    a = 0.f;
    #pragma unroll 8
    for (int k = 0; k < NO; ++k) a += ev[k] * Wp[k * PH + t];
    (enc ? PB : PA)[row * PH + t] = a;
}

// ---------------- pair scores ----------------
__global__ __launch_bounds__(128) void k_pair(
    const float* __restrict__ PA, const float* __restrict__ PB,
    const float* __restrict__ bp1, const float* __restrict__ Wp2,
    const float* __restrict__ bp2, float* __restrict__ s_pair)
{
    const int i = blockIdx.x;
    const int j = threadIdx.x;
    __shared__ float pa[PH];
    __shared__ float b1s[PH];
    __shared__ float w2s[PH];
    pa[j]  = PA[i * PH + j];
    b1s[j] = bp1[j];
    w2s[j] = Wp2[j];
    __syncthreads();
    const float* pb = PB + j * PH;
    float acc = 0.f;
    #pragma unroll 8
    for (int c = 0; c < PH; ++c)
        acc += w2s[c] * fmaxf(pa[c] + pb[c] + b1s[c], 0.f);
    float z = acc + bp2[0];
    float sp = fmaxf(z, 0.f) + log1pf(__expf(-fabsf(z)));
    s_pair[i * 128 + j] = sp;
}

// ------- counting sort by length, DESCENDING, one block, LDS atomics -------
__global__ __launch_bounds__(1024) void k_sort(
    const int* __restrict__ lengths, int* __restrict__ perm)
{
    __shared__ int cnt[130];
    __shared__ int suf[130];
    const int t = threadIdx.x;
    if (t < 130) cnt[t] = 0;
    __syncthreads();
    for (int i = t; i < 16384; i += 1024) atomicAdd(&cnt[lengths[i]], 1);
    __syncthreads();
    if (t < 130) suf[t] = cnt[t];
    __syncthreads();
    for (int d = 1; d < 130; d <<= 1) {
        int v = 0;
        if (t < 130) { v = suf[t]; if (t + d < 130) v += suf[t + d]; }
        __syncthreads();
        if (t < 130) suf[t] = v;
        __syncthreads();
    }
    if (t < 129) cnt[t] = (t + 1 < 130) ? suf[t + 1] : 0;
    __syncthreads();
    for (int i = t; i < 16384; i += 1024) {
        int pos = atomicAdd(&cnt[lengths[i]], 1);
        perm[pos] = i;
    }
}

// ---- GRU: one wave per 16-pair group; the wave owns ALL 64 hidden dims ----
// grid 1024 x 64. NO __syncthreads in the recurrence: h recirculates through a
// wave-private LDS buffer (same-wave DS ops are in-order). lane(q=l>>4,n=l&15):
// pair = n; D-tile mt gives hidden cols 16*mt + 4q + r.
// Biases for r/z/xn are folded into the spare k=16 column of the x K-tile
// (ax[16] = 1.0 via lane q==2,j==0); only b_hh(n) stays as a C-init (c_hn).
__global__ __launch_bounds__(64, 1) void k_gru(
    const float* __restrict__ seqs, const int* __restrict__ lengths,
    const int* __restrict__ perm,
    const float* __restrict__ W_ih, const float* __restrict__ b_ih,
    const float* __restrict__ W_hh, const float* __restrict__ b_hh,
    const float* __restrict__ Ws, const float* __restrict__ bs,
    const float* __restrict__ s_pair, float* __restrict__ d_out)
{
    __shared__ __align__(16) f16 hbuf[16 * 72];   // [pair][64 + 8 pad]
    const int tid = threadIdx.x;
    const int q = tid >> 4;
    const int n = tid & 15;
    const int pb = blockIdx.x * 16;
    const float S_RZ = -1.4426950408889634f;   // -log2(e)
    const float S_N  =  2.8853900817779268f;   // 2*log2(e)

    // A-fragments: wh[g][mt][ks] = gate g, hidden-out cols [16mt,16mt+16),
    // h-dims [32ks,32ks+32). wi[g][mt] = x-dims 0..15 plus bias at k==16.
    f16x8 wh[3][4][2], wi[3][4];
    f32x4 c_hn[4];
    #pragma unroll
    for (int g = 0; g < 3; ++g) {
        const float s = (g < 2) ? S_RZ : S_N;
        #pragma unroll
        for (int mt = 0; mt < 4; ++mt) {
            const int col = g * 64 + mt * 16 + n;
            #pragma unroll
            for (int ks = 0; ks < 2; ++ks)
                #pragma unroll
                for (int j = 0; j < 8; ++j)
                    wh[g][mt][ks][j] = (f16)(W_hh[(ks * 32 + q * 8 + j) * 192 + col] * s);
            #pragma unroll
            for (int j = 0; j < 8; ++j) {
                const int k = q * 8 + j;
                float v = 0.f;
                if (k < FE_N) {
                    v = W_ih[k * 192 + col] * s;
                } else if (k == FE_N) {          // bias rides the ax[16]=1 slot
                    const int c0 = mt * 16 + n;
                    v = (g == 0) ? S_RZ * (b_ih[c0] + b_hh[c0])
                      : (g == 1) ? S_RZ * (b_ih[64 + c0] + b_hh[64 + c0])
                                 : S_N * b_ih[128 + c0];
                }
                wi[g][mt][j] = (f16)v;
            }
        }
    }
    #pragma unroll
    for (int mt = 0; mt < 4; ++mt)
        #pragma unroll
        for (int r = 0; r < 4; ++r)
            c_hn[mt][r] = S_N * b_hh[128 + mt * 16 + q * 4 + r];

    const int myp   = perm[pb + n];
    const int mylen = lengths[myp];
    int ml = mylen;
    ml = max(ml, __shfl_xor(ml, 1));
    ml = max(ml, __shfl_xor(ml, 2));
    ml = max(ml, __shfl_xor(ml, 4));
    ml = max(ml, __shfl_xor(ml, 8));
    const int maxlen = __builtin_amdgcn_readfirstlane(ml);

    // zero h (1152 f16 = 144 x 8); same-wave in-order LDS, no barrier needed
    {
        f16x8 z8 = {};
        #pragma unroll
        for (int i = 0; i < 3; ++i) {
            int idx = tid + i * 64;
            if (idx < 144) *(f16x8*)&hbuf[idx * 8] = z8;
        }
    }

    // x stream: lanes q<2 hold pair n's feats [8q,8q+8); 2-step prefetch
    const float4* xp = (const float4*)(seqs + (size_t)myp * (T_MAX * FE_N)) + q * 2;
    float4 x0a = {0.f, 0.f, 0.f, 0.f}, x0b = x0a, x1a = x0a, x1b = x0a;
    if (q < 2) {
        x0a = xp[0]; x0b = xp[1];        // row t=0
        x1a = xp[4]; x1b = xp[5];        // row t=1 (always allocated)
    }
    f16x8 ax = {};
    if (q == 2) ax[0] = (f16)1.f;        // constant bias column k=16
    const f32x4 zc = {0.f, 0.f, 0.f, 0.f};
    float hold[4][4] = {};

    auto step = [&](int TT, float4& XA, float4& XB) {
        f16x8 bh0 = *(const f16x8*)&hbuf[n * 72 + 8 * q];
        f16x8 bh1 = *(const f16x8*)&hbuf[n * 72 + 32 + 8 * q];
        if (q < 2) {
            ax[0] = (f16)XA.x; ax[1] = (f16)XA.y;
            ax[2] = (f16)XA.z; ax[3] = (f16)XA.w;
            ax[4] = (f16)XB.x; ax[5] = (f16)XB.y;
            ax[6] = (f16)XB.z; ax[7] = (f16)XB.w;
            int tn = (TT + 2 < maxlen) ? (TT + 2) : (maxlen - 1);
            XA = xp[tn * 4]; XB = xp[tn * 4 + 1];
        }
        const bool live = (TT < mylen);
        #pragma unroll
        for (int mt = 0; mt < 4; ++mt) {
            f32x4 ar = __builtin_amdgcn_mfma_f32_16x16x32_f16(wh[0][mt][0], bh0, zc, 0, 0, 0);
            ar = __builtin_amdgcn_mfma_f32_16x16x32_f16(wh[0][mt][1], bh1, ar, 0, 0, 0);
            ar = __builtin_amdgcn_mfma_f32_16x16x32_f16(wi[0][mt],    ax,  ar, 0, 0, 0);
            f32x4 az = __builtin_amdgcn_mfma_f32_16x16x32_f16(wh[1][mt][0], bh0, zc, 0, 0, 0);
            az = __builtin_amdgcn_mfma_f32_16x16x32_f16(wh[1][mt][1], bh1, az, 0, 0, 0);
            az = __builtin_amdgcn_mfma_f32_16x16x32_f16(wi[1][mt],    ax,  az, 0, 0, 0);
            f32x4 hn = __builtin_amdgcn_mfma_f32_16x16x32_f16(wh[2][mt][0], bh0, c_hn[mt], 0, 0, 0);
            hn = __builtin_amdgcn_mfma_f32_16x16x32_f16(wh[2][mt][1], bh1, hn, 0, 0, 0);
            f32x4 xn = __builtin_amdgcn_mfma_f32_16x16x32_f16(wi[2][mt], ax, zc, 0, 0, 0);
            f16x4 hv4;
            #pragma unroll
            for (int r = 0; r < 4; ++r) {
                float rg    = __builtin_amdgcn_rcpf(1.f + __builtin_amdgcn_exp2f(ar[r]));
                float zg    = __builtin_amdgcn_rcpf(1.f + __builtin_amdgcn_exp2f(az[r]));
                float inner = fmaf(rg, hn[r], xn[r]);
                float nn    = fmaf(-2.f, __builtin_amdgcn_rcpf(1.f + __builtin_amdgcn_exp2f(inner)), 1.f);
                float hnew  = fmaf(zg, hold[mt][r] - nn, nn);
                hold[mt][r] = live ? hnew : hold[mt][r];
                hv4[r] = (f16)hold[mt][r];
            }
            *(f16x4*)&hbuf[n * 72 + mt * 16 + 4 * q] = hv4;
        }
    };

    #pragma unroll 1
    for (int t = 0; t < maxlen; t += 2) {
        step(t, x0a, x0b);
        if (t + 1 < maxlen) step(t + 1, x1a, x1b);   // wave-uniform
    }

    // epilogue: p_seq = sigmoid(h @ Ws + bs); contrib = s_pair * p_seq
    float part = 0.f;
    #pragma unroll
    for (int mt = 0; mt < 4; ++mt)
        #pragma unroll
        for (int r = 0; r < 4; ++r)
            part += hold[mt][r] * Ws[mt * 16 + q * 4 + r];
    part += __shfl_xor(part, 16);
    part += __shfl_xor(part, 32);        // full 64-dim dot for pair n
    if (tid < 16) {
        float pv = fast_sigmoid(part + bs[0]);
        float contrib = s_pair[myp] * pv;
        #pragma unroll
        for (int off = 1; off < 16; off <<= 1)
            contrib += __shfl_xor(contrib, off);
        if (tid == 0) atomicAdd(d_out, contrib);
    }
}

extern "C" void kernel_launch(void* const* d_in, const int* in_sizes, int n_in,
                              void* d_out, int out_size, void* d_ws, size_t ws_size,
                              hipStream_t stream)
{
    const float* O_feats = (const float*)d_in[0];
    const float* D_feats = (const float*)d_in[1];
    const float* seqs    = (const float*)d_in[2];
    const int*   lengths = (const int*)d_in[3];
    const float* WO1 = (const float*)d_in[4];  const float* bO1 = (const float*)d_in[5];
    const float* WO2 = (const float*)d_in[6];  const float* bO2 = (const float*)d_in[7];
    const float* WO3 = (const float*)d_in[8];  const float* bO3 = (const float*)d_in[9];
    const float* WD1 = (const float*)d_in[10]; const float* bD1 = (const float*)d_in[11];
    const float* WD2 = (const float*)d_in[12]; const float* bD2 = (const float*)d_in[13];
    const float* WD3 = (const float*)d_in[14]; const float* bD3 = (const float*)d_in[15];
    const float* Wp1 = (const float*)d_in[16]; const float* bp1 = (const float*)d_in[17];
    const float* Wp2 = (const float*)d_in[18]; const float* bp2 = (const float*)d_in[19];
    const float* W_ih = (const float*)d_in[20]; const float* b_ih = (const float*)d_in[21];
    const float* W_hh = (const float*)d_in[22]; const float* b_hh = (const float*)d_in[23];
    const float* Ws   = (const float*)d_in[24]; const float* bs   = (const float*)d_in[25];

    float* out    = (float*)d_out;
    float* PA     = (float*)d_ws;              // 16384 f
    float* PB     = PA + 128 * 128;            // 16384 f
    float* s_pair = PB + 128 * 128;            // 16384 f
    int*   perm   = (int*)(s_pair + 16384);    // 16384 i

    k_enc<<<256, 128, 0, stream>>>(O_feats, D_feats,
                                   WO1, bO1, WO2, bO2, WO3, bO3,
                                   WD1, bD1, WD2, bD2, WD3, bD3,
                                   Wp1, PA, PB, out);
    k_pair<<<128, 128, 0, stream>>>(PA, PB, bp1, Wp2, bp2, s_pair);
    k_sort<<<1, 1024, 0, stream>>>(lengths, perm);
    k_gru<<<1024, 64, 0, stream>>>(seqs, lengths, perm, W_ih, b_ih, W_hh, b_hh,
                                   Ws, bs, s_pair, out);
}

// Round 3
// 378.908 us; speedup vs baseline: 1.0773x; 1.0773x over previous
//
#include <hip/hip_runtime.h>
#include <hip/hip_bf16.h>

#define O_N 128
#define D_N 128
#define F_LS 64
#define T_MAX 128
#define FE_N 16
#define H_GRU 64
#define NH 128
#define NO 64
#define PH 128
#define ENG 4

typedef _Float16 f16;
typedef __fp16 hf2 __attribute__((ext_vector_type(2)));
typedef f16 f16x4 __attribute__((ext_vector_type(4)));
typedef f16 f16x8 __attribute__((ext_vector_type(8)));
typedef float f32x4 __attribute__((ext_vector_type(4)));

__device__ __forceinline__ float fast_sigmoid(float x) {
    return __builtin_amdgcn_rcpf(1.f + __expf(-x));
}

// ---------------- encoders + PA/PB precompute (also zeroes d_out) ----------
__global__ __launch_bounds__(128) void k_enc(
    const float* __restrict__ O_feats, const float* __restrict__ D_feats,
    const float* __restrict__ WO1, const float* __restrict__ bO1,
    const float* __restrict__ WO2, const float* __restrict__ bO2,
    const float* __restrict__ WO3, const float* __restrict__ bO3,
    const float* __restrict__ WD1, const float* __restrict__ bD1,
    const float* __restrict__ WD2, const float* __restrict__ bD2,
    const float* __restrict__ WD3, const float* __restrict__ bD3,
    const float* __restrict__ Wp1,
    float* __restrict__ PA, float* __restrict__ PB, float* __restrict__ d_out)
{
    __shared__ float h1[NH];
    __shared__ float h2[NH];
    __shared__ float ev[NO];
    const int b = blockIdx.x;
    const int enc = b >> 7;
    const int row = b & 127;
    const int t = threadIdx.x;
    if (b == 0 && t == 0) d_out[0] = 0.f;

    const float* x  = (enc ? D_feats : O_feats) + row * F_LS;
    const float* W1 = enc ? WD1 : WO1;  const float* b1 = enc ? bD1 : bO1;
    const float* W2 = enc ? WD2 : WO2;  const float* b2 = enc ? bD2 : bO2;
    const float* W3 = enc ? WD3 : WO3;  const float* b3 = enc ? bD3 : bO3;

    float a = b1[t];
    #pragma unroll 8
    for (int k = 0; k < F_LS; ++k) a += x[k] * W1[k * NH + t];
    h1[t] = fmaxf(a, 0.f);
    __syncthreads();

    a = b2[t];
    #pragma unroll 8
    for (int k = 0; k < NH; ++k) a += h1[k] * W2[k * NH + t];
    h2[t] = fmaxf(a, 0.f);
    __syncthreads();

    if (t < NO) {
        a = b3[t];
        #pragma unroll 8
        for (int k = 0; k < NH; ++k) a += h2[k] * W3[k * NO + t];
        ev[t] = a;
    }
    __syncthreads();

    const float* Wp = Wp1 + (enc ? NO * PH : 0);
    a = 0.f;
    #pragma unroll 8
    for (int k = 0; k < NO; ++k) a += ev[k] * Wp[k * PH + t];
    (enc ? PB : PA)[row * PH + t] = a;
}

// ---------------- pair scores ----------------
__global__ __launch_bounds__(128) void k_pair(
    const float* __restrict__ PA, const float* __restrict__ PB,
    const float* __restrict__ bp1, const float* __restrict__ Wp2,
    const float* __restrict__ bp2, float* __restrict__ s_pair)
{
    const int i = blockIdx.x;
    const int j = threadIdx.x;
    __shared__ float pa[PH];
    __shared__ float b1s[PH];
    __shared__ float w2s[PH];
    pa[j]  = PA[i * PH + j];
    b1s[j] = bp1[j];
    w2s[j] = Wp2[j];
    __syncthreads();
    const float* pb = PB + j * PH;
    float acc = 0.f;
    #pragma unroll 8
    for (int c = 0; c < PH; ++c)
        acc += w2s[c] * fmaxf(pa[c] + pb[c] + b1s[c], 0.f);
    float z = acc + bp2[0];
    float sp = fmaxf(z, 0.f) + log1pf(__expf(-fabsf(z)));
    s_pair[i * 128 + j] = sp;
}

// ------- counting sort by length, DESCENDING, one block, LDS atomics -------
__global__ __launch_bounds__(1024) void k_sort(
    const int* __restrict__ lengths, int* __restrict__ perm)
{
    __shared__ int cnt[130];
    __shared__ int suf[130];
    const int t = threadIdx.x;
    if (t < 130) cnt[t] = 0;
    __syncthreads();
    for (int i = t; i < 16384; i += 1024) atomicAdd(&cnt[lengths[i]], 1);
    __syncthreads();
    if (t < 130) suf[t] = cnt[t];
    __syncthreads();
    for (int d = 1; d < 130; d <<= 1) {
        int v = 0;
        if (t < 130) { v = suf[t]; if (t + d < 130) v += suf[t + d]; }
        __syncthreads();
        if (t < 130) suf[t] = v;
        __syncthreads();
    }
    if (t < 129) cnt[t] = (t + 1 < 130) ? suf[t + 1] : 0;
    __syncthreads();
    for (int i = t; i < 16384; i += 1024) {
        int pos = atomicAdd(&cnt[lengths[i]], 1);
        perm[pos] = i;
    }
}

// ---- GRU: 4 engines (16-pair groups of ADJACENT sorted rank) per block ----
// grid 256 x 1024. 16 waves/block = 4 engines x 4 waves -> 4 waves/SIMD for
// the block's entire lifetime (equal-length co-scheduling: wall = longest
// quad at full concurrency, no 4->1 concurrency decay).
// Engine e, wave wi_: owns hidden cols [16*wi_,16*wi_+16) of group (4*blk+e).
// lane(q=l>>4,n=l&15): pair = n, cols 16*wi_+4q+0..3. One barrier per step.
// MFMA x-first: first MFMA per gate has no LDS dependency.
__global__ __launch_bounds__(1024, 4) void k_gru(
    const float* __restrict__ seqs, const int* __restrict__ lengths,
    const int* __restrict__ perm,
    const float* __restrict__ W_ih, const float* __restrict__ b_ih,
    const float* __restrict__ W_hh, const float* __restrict__ b_hh,
    const float* __restrict__ Ws, const float* __restrict__ bs,
    const float* __restrict__ s_pair, float* __restrict__ d_out)
{
    __shared__ __align__(16) f16 hbuf[ENG][2][16 * 72];  // [eng][buf][pair][64+8]
    __shared__ float red[ENG][64];
    const int tid = threadIdx.x;
    const int wave = tid >> 6;
    const int e = wave >> 2;              // engine
    const int wi_ = wave & 3;             // wave-in-engine
    const int l  = tid & 63;
    const int q  = l >> 4;
    const int n  = l & 15;
    const int c  = wi_ * 16 + n;          // W-frag column (m-row of A-tile)
    const int colbase = wi_ * 16 + q * 4; // this lane's 4 hidden cols
    const int pb = blockIdx.x * 64 + e * 16;
    const float S_RZ = -1.4426950408889634f;   // -log2(e)
    const float S_N  =  2.8853900817779268f;   // 2*log2(e)

    // W fragments (A-operand via m=lane&15):
    f16x8 wh[3][2], wi[3];
    #pragma unroll
    for (int g = 0; g < 3; ++g) {
        const int gb = g * 64;
        const float s = (g < 2) ? S_RZ : S_N;
        #pragma unroll
        for (int ks = 0; ks < 2; ++ks)
            #pragma unroll
            for (int j = 0; j < 8; ++j)
                wh[g][ks][j] = (f16)(W_hh[(ks * 32 + q * 8 + j) * 192 + gb + c] * s);
        #pragma unroll
        for (int j = 0; j < 8; ++j) {
            int k = q * 8 + j;
            wi[g][j] = (k < FE_N) ? (f16)(W_ih[k * 192 + gb + c] * s) : (f16)0.f;
        }
    }
    // per-reg bias C-vectors and Ws for this lane's 4 cols
    f32x4 c_r, c_z, c_hn, c_xn;
    float wsc[4];
    #pragma unroll
    for (int r = 0; r < 4; ++r) {
        int col = colbase + r;
        c_r[r]  = S_RZ * (b_ih[col] + b_hh[col]);
        c_z[r]  = S_RZ * (b_ih[64 + col] + b_hh[64 + col]);
        c_hn[r] = S_N * b_hh[128 + col];
        c_xn[r] = S_N * b_ih[128 + col];
        wsc[r]  = Ws[col];
    }
    const int myp   = perm[pb + n];                       // this lane's pair
    const int mylen = lengths[myp];
    const int elen  = lengths[perm[pb]];                  // engine max (sorted desc)
    const int blen  = lengths[perm[blockIdx.x * 64]];     // block max

    // zero all h buffers (4 eng x 2 buf x 1152 f16 = 1152 x f16x8 chunks)
    {
        f16x8 z8 = {};
        f16* hb = (f16*)hbuf;
        #pragma unroll 2
        for (int i = tid; i < 1152; i += 1024) *(f16x8*)&hb[i * 8] = z8;
    }

    // x: lanes q<2 stream pair n's feats [8q,8q+8) from global, per-sub buffers
    const float4* xp = (const float4*)(seqs + (size_t)myp * (T_MAX * FE_N)) + q * 2;
    float4 x0a = {0.f, 0.f, 0.f, 0.f}, x0b = x0a, x1a = x0a, x1b = x0a;
    if (q < 2) {
        x0a = xp[0]; x0b = xp[1];        // row t=0
        x1a = xp[4]; x1b = xp[5];        // row t=1 (rows always allocated)
    }
    f16x8 ax = {};                        // q>=2 lanes contribute zeros (K pad)
    float hold[4] = {0.f, 0.f, 0.f, 0.f};
    __syncthreads();

    auto step = [&](int TT, int sub, float4& XA, float4& XB) {
        const f16* hb  = hbuf[e][sub];
        f16*       hbw = hbuf[e][sub ^ 1];
        // issue LDS reads first (latency), then x-side work fills the gap
        f16x8 bh0 = *(const f16x8*)&hb[n * 72 + 8 * q];
        f16x8 bh1 = *(const f16x8*)&hb[n * 72 + 32 + 8 * q];
        if (q < 2) {
            union { f16x8 v8; hf2 v2[4]; } u;
            u.v2[0] = __builtin_amdgcn_cvt_pkrtz(XA.x, XA.y);
            u.v2[1] = __builtin_amdgcn_cvt_pkrtz(XA.z, XA.w);
            u.v2[2] = __builtin_amdgcn_cvt_pkrtz(XB.x, XB.y);
            u.v2[3] = __builtin_amdgcn_cvt_pkrtz(XB.z, XB.w);
            ax = u.v8;
            int tn = (TT + 2 < elen) ? (TT + 2) : (elen - 1);
            XA = xp[tn * 4]; XB = xp[tn * 4 + 1];
        }
        // x-first MFMA chains (no LDS dep on first op of r/z/xn)
        f32x4 ar = __builtin_amdgcn_mfma_f32_16x16x32_f16(wi[0], ax, c_r, 0, 0, 0);
        f32x4 az = __builtin_amdgcn_mfma_f32_16x16x32_f16(wi[1], ax, c_z, 0, 0, 0);
        f32x4 xn = __builtin_amdgcn_mfma_f32_16x16x32_f16(wi[2], ax, c_xn, 0, 0, 0);
        ar = __builtin_amdgcn_mfma_f32_16x16x32_f16(wh[0][0], bh0, ar, 0, 0, 0);
        ar = __builtin_amdgcn_mfma_f32_16x16x32_f16(wh[0][1], bh1, ar, 0, 0, 0);
        az = __builtin_amdgcn_mfma_f32_16x16x32_f16(wh[1][0], bh0, az, 0, 0, 0);
        az = __builtin_amdgcn_mfma_f32_16x16x32_f16(wh[1][1], bh1, az, 0, 0, 0);
        f32x4 hn = __builtin_amdgcn_mfma_f32_16x16x32_f16(wh[2][0], bh0, c_hn, 0, 0, 0);
        hn = __builtin_amdgcn_mfma_f32_16x16x32_f16(wh[2][1], bh1, hn, 0, 0, 0);

        const bool live = (TT < mylen);
        #pragma unroll
        for (int r = 0; r < 4; ++r) {
            float rg    = __builtin_amdgcn_rcpf(1.f + __builtin_amdgcn_exp2f(ar[r]));
            float zg    = __builtin_amdgcn_rcpf(1.f + __builtin_amdgcn_exp2f(az[r]));
            float inner = fmaf(rg, hn[r], xn[r]);
            float nn    = fmaf(-2.f, __builtin_amdgcn_rcpf(1.f + __builtin_amdgcn_exp2f(inner)), 1.f);
            float hnew  = fmaf(zg, hold[r] - nn, nn);
            hold[r] = live ? hnew : hold[r];
        }
        union { f16x4 v4; hf2 v2[2]; } hu;
        hu.v2[0] = __builtin_amdgcn_cvt_pkrtz(hold[0], hold[1]);
        hu.v2[1] = __builtin_amdgcn_cvt_pkrtz(hold[2], hold[3]);
        *(f16x4*)&hbw[n * 72 + colbase] = hu.v4;
    };

    #pragma unroll 1
    for (int t = 0; t < blen; t += 2) {
        if (t < elen) step(t, 0, x0a, x0b);
        __syncthreads();
        if (t + 1 >= blen) break;                 // block-uniform
        if (t + 1 < elen) step(t + 1, 1, x1a, x1b);
        __syncthreads();
    }

    // epilogue: p_seq = sigmoid(h @ Ws + bs); contrib = s_pair * p_seq
    float part = hold[0] * wsc[0] + hold[1] * wsc[1] +
                 hold[2] * wsc[2] + hold[3] * wsc[3];
    part += __shfl_xor(part, 16);
    part += __shfl_xor(part, 32);          // sum over q: wave partial for pair n
    if (l < 16) red[e][wi_ * 16 + n] = part;
    __syncthreads();
    if (tid < 64) {
        const int eo = tid >> 4;
        const int nn_ = tid & 15;
        float s = red[eo][nn_] + red[eo][16 + nn_] + red[eo][32 + nn_] + red[eo][48 + nn_];
        float pv = fast_sigmoid(s + bs[0]);
        float contrib = s_pair[perm[blockIdx.x * 64 + eo * 16 + nn_]] * pv;
        contrib += __shfl_xor(contrib, 1);
        contrib += __shfl_xor(contrib, 2);
        contrib += __shfl_xor(contrib, 4);
        contrib += __shfl_xor(contrib, 8);
        if (nn_ == 0) atomicAdd(d_out, contrib);
    }
}

extern "C" void kernel_launch(void* const* d_in, const int* in_sizes, int n_in,
                              void* d_out, int out_size, void* d_ws, size_t ws_size,
                              hipStream_t stream)
{
    const float* O_feats = (const float*)d_in[0];
    const float* D_feats = (const float*)d_in[1];
    const float* seqs    = (const float*)d_in[2];
    const int*   lengths = (const int*)d_in[3];
    const float* WO1 = (const float*)d_in[4];  const float* bO1 = (const float*)d_in[5];
    const float* WO2 = (const float*)d_in[6];  const float* bO2 = (const float*)d_in[7];
    const float* WO3 = (const float*)d_in[8];  const float* bO3 = (const float*)d_in[9];
    const float* WD1 = (const float*)d_in[10]; const float* bD1 = (const float*)d_in[11];
    const float* WD2 = (const float*)d_in[12]; const float* bD2 = (const float*)d_in[13];
    const float* WD3 = (const float*)d_in[14]; const float* bD3 = (const float*)d_in[15];
    const float* Wp1 = (const float*)d_in[16]; const float* bp1 = (const float*)d_in[17];
    const float* Wp2 = (const float*)d_in[18]; const float* bp2 = (const float*)d_in[19];
    const float* W_ih = (const float*)d_in[20]; const float* b_ih = (const float*)d_in[21];
    const float* W_hh = (const float*)d_in[22]; const float* b_hh = (const float*)d_in[23];
    const float* Ws   = (const float*)d_in[24]; const float* bs   = (const float*)d_in[25];

    float* out    = (float*)d_out;
    float* PA     = (float*)d_ws;              // 16384 f
    float* PB     = PA + 128 * 128;            // 16384 f
    float* s_pair = PB + 128 * 128;            // 16384 f
    int*   perm   = (int*)(s_pair + 16384);    // 16384 i

    k_enc<<<256, 128, 0, stream>>>(O_feats, D_feats,
                                   WO1, bO1, WO2, bO2, WO3, bO3,
                                   WD1, bD1, WD2, bD2, WD3, bD3,
                                   Wp1, PA, PB, out);
    k_pair<<<128, 128, 0, stream>>>(PA, PB, bp1, Wp2, bp2, s_pair);
    k_sort<<<1, 1024, 0, stream>>>(lengths, perm);
    k_gru<<<256, 1024, 0, stream>>>(seqs, lengths, perm, W_ih, b_ih, W_hh, b_hh,
                                    Ws, bs, s_pair, out);
}